// Round 9
// baseline (1087.862 us; speedup 1.0000x reference)
//
#include <hip/hip_runtime.h>
#include <hip/hip_bf16.h>
#include <cstdint>
#include <cstddef>

// B=64 T=512 E=768 H=256 L=9.  BiLSTM + linear + CRF loglik (scalar out).
// R12: lstm_k is near its structural floor (step = MFMA 1.0k + VALU 0.8k +
// sync 0.7k, phases barrier-serialized; MFMA per CU invariant under batch
// split).  This round attacks the OTHER 522us: gemm_xg ported to the m97
// structure -- global_load_lds width=16 direct HBM->LDS staging (compiler
// never auto-emits it; measured +69% on this exact shape), linear [128][64]
// LDS (pad removed: global_load_lds writes base+lane*16 contiguously).
// lstm_k: only a riskless micro-opt -- loop-invariant zero vector as MFMA
// C-input (kills 32 v_mov acc-zeroing per thread per step).

typedef __attribute__((ext_vector_type(8))) short short8;
typedef __attribute__((ext_vector_type(4))) float floatx4;
typedef __attribute__((ext_vector_type(2))) float floatx2;
typedef __attribute__((ext_vector_type(8))) int v8i;
typedef unsigned short ushort_t;
typedef unsigned char uchar_t;
typedef unsigned int uint_t;
typedef unsigned long long ull_t;

#define NB   64
#define NT   512
#define NE   768
#define NH   256
#define NL   9
#define NG   1024   // 4*H
#define NCC  2048   // both dirs' gates
#define HPAD 272    // LDS h row stride (bytes, fp8)

__device__ inline float asf(uint_t u) {
    union { uint_t i; float f; } v; v.i = u; return v.f;
}
__device__ inline ushort_t f2b(float f) {
    union { float f; uint_t i; } v; v.f = f;
    uint_t r = (v.i + 0x7FFFu + ((v.i >> 16) & 1u)) >> 16;
    return (ushort_t)r;
}

// Direct HBM->LDS 16B async copy (emits global_load_lds_dwordx4).
__device__ inline void g2lds16(const void* g, void* l) {
    __builtin_amdgcn_global_load_lds(
        (const __attribute__((address_space(1))) uint_t*)g,
        (__attribute__((address_space(3))) uint_t*)l, 16, 0, 0);
}

// ---------------- K1: embeddings (B,T,E) f32 -> xbf (T,B,E) bf16 ------------
__global__ void conv_x(const float* __restrict__ emb, ushort_t* __restrict__ xbf) {
    int id = blockIdx.x * blockDim.x + threadIdx.x;      // over T*B*(E/4)
    int t  = id / (NB * (NE / 4));
    int rm = id - t * (NB * (NE / 4));
    int b  = rm / (NE / 4);
    int e4 = rm - b * (NE / 4);
    const float4 v = *(const float4*)(emb + ((size_t)b * NT + t) * NE + e4 * 4);
    ushort_t o[4] = { f2b(v.x), f2b(v.y), f2b(v.z), f2b(v.w) };
    *(uint2*)(xbf + ((size_t)t * NB + b) * NE + e4 * 4) = *(const uint2*)o;
}

// ---------------- K1b: weights. Row interleave: row' = d*1024 + hu*4 + gate -
// Rows prescaled: i,f,o by log2(e); g by 2*log2(e)  (log2-domain gates).
__global__ void conv_w(const float* __restrict__ Wihf, const float* __restrict__ Wihb,
                       const float* __restrict__ Whhf, const float* __restrict__ Whhb,
                       const float* __restrict__ bf,   const float* __restrict__ bb,
                       ushort_t* __restrict__ wcat, uchar_t* __restrict__ whh8,
                       float* __restrict__ bias) {
    int idx = blockIdx.x * blockDim.x + threadIdx.x;
    const int NW1 = NCC * NE;            // 1572864
    const int NW2 = NCC * NH / 2;        // 262144 fp8 pairs
    const float SC1 = 1.4426950408889634f;
    const float SC2 = 2.8853900817779268f;
    if (idx < NW1) {
        int rowp = idx / NE, col = idx - rowp * NE;
        int d = rowp >> 10, rr = rowp & 1023;
        int hu = rr >> 2, gate = rr & 3;
        float sc = (gate == 2) ? SC2 : SC1;
        const float* W = d ? Wihb : Wihf;
        wcat[idx] = f2b(W[(size_t)(gate * NH + hu) * NE + col] * sc);
    } else if (idx < NW1 + NW2) {
        int j = idx - NW1;
        int rowp = j >> 7, kp = (j & 127) * 2;
        int d = rowp >> 10, rr = rowp & 1023;
        int hu = rr >> 2, gate = rr & 3;
        float sc = (gate == 2) ? SC2 : SC1;
        const float* W = d ? Whhb : Whhf;
        float f0 = W[(size_t)(gate * NH + hu) * NH + kp] * sc;
        float f1 = W[(size_t)(gate * NH + hu) * NH + kp + 1] * sc;
        uint_t pk = __builtin_amdgcn_cvt_pk_fp8_f32(f0, f1, 0, false);
        *(ushort_t*)(whh8 + (size_t)rowp * NH + kp) = (ushort_t)(pk & 0xFFFF);
    } else if (idx < NW1 + NW2 + NCC) {
        int rowp = idx - NW1 - NW2;
        int d = rowp >> 10, rr = rowp & 1023;
        int hu = rr >> 2, gate = rr & 3;
        float sc = (gate == 2) ? SC2 : SC1;
        bias[rowp] = (d ? bb : bf)[gate * NH + hu] * sc;
    }
}

// ---------------- K2: xg = xbf(32768x768) @ wcat^T(2048x768) + bias ---------
// m97 structure: linear [128][64] LDS, global_load_lds width=16 staging
// (8 x 16B per thread per K-tile), 2-barrier loop, 4 waves x 4x4 16-tiles.
__global__ __launch_bounds__(256) void gemm_xg(const ushort_t* __restrict__ A,
                                               const ushort_t* __restrict__ W,
                                               const float* __restrict__ bias,
                                               ushort_t* __restrict__ C) {
    __shared__ __align__(16) ushort_t As[128 * 64];
    __shared__ __align__(16) ushort_t Bs[128 * 64];
    const int tid = threadIdx.x;
    const int wave = tid >> 6, lane = tid & 63;
    const int q = lane >> 4, m16 = lane & 15;
    const int wm = wave & 1, wn = wave >> 1;
    const int m0 = blockIdx.y * 128, n0 = blockIdx.x * 128;

    floatx4 acc[4][4];
    #pragma unroll
    for (int i = 0; i < 4; ++i)
        #pragma unroll
        for (int j = 0; j < 4; ++j) acc[i][j] = (floatx4){0.f, 0.f, 0.f, 0.f};

    for (int kt = 0; kt < NE / 64; ++kt) {
        __syncthreads();
        // Stage A,B tiles: chunk = 16B unit; row = chunk>>3, kc = chunk&7.
        // LDS dest = chunk*16 bytes -> wave-uniform base + lane*16.  ✓
        #pragma unroll
        for (int it = 0; it < 4; ++it) {
            int chunk = tid + it * 256;         // 0..1023
            int row = chunk >> 3, kc = chunk & 7;
            g2lds16(A + (size_t)(m0 + row) * NE + kt * 64 + kc * 8,
                    (uchar_t*)As + chunk * 16);
            g2lds16(W + (size_t)(n0 + row) * NE + kt * 64 + kc * 8,
                    (uchar_t*)Bs + chunk * 16);
        }
        __syncthreads();                        // implicit vmcnt(0) drain
        #pragma unroll
        for (int ks = 0; ks < 2; ++ks) {
            short8 af[4], bfr[4];
            #pragma unroll
            for (int mt = 0; mt < 4; ++mt)
                af[mt] = *(const short8*)(&As[(wm * 64 + mt * 16 + m16) * 64 + ks * 32 + q * 8]);
            #pragma unroll
            for (int nt = 0; nt < 4; ++nt)
                bfr[nt] = *(const short8*)(&Bs[(wn * 64 + nt * 16 + m16) * 64 + ks * 32 + q * 8]);
            #pragma unroll
            for (int mt = 0; mt < 4; ++mt)
                #pragma unroll
                for (int nt = 0; nt < 4; ++nt)
                    acc[mt][nt] = __builtin_amdgcn_mfma_f32_16x16x32_bf16(
                        af[mt], bfr[nt], acc[mt][nt], 0, 0, 0);
        }
    }
    float bcol[4];
    #pragma unroll
    for (int nt = 0; nt < 4; ++nt) bcol[nt] = bias[n0 + wn * 64 + nt * 16 + m16];
    #pragma unroll
    for (int mt = 0; mt < 4; ++mt)
        #pragma unroll
        for (int nt = 0; nt < 4; ++nt) {
            int gn = n0 + wn * 64 + nt * 16 + m16;
            #pragma unroll
            for (int r = 0; r < 4; ++r) {
                int gm = m0 + wm * 64 + mt * 16 + q * 4 + r;
                C[(size_t)gm * NCC + gn] = f2b(acc[mt][nt][r] + bcol[nt]);
            }
        }
}

// ---------------- scalar log2-domain LSTM gate (verified R8) ----------------
__device__ inline uchar_t lstm_gate(floatx4 a, ull_t xr, float& cc) {
    uint_t lo = (uint_t)xr, hi = (uint_t)(xr >> 32);
    float pi = a[0] + asf(lo << 16);
    float pf = a[1] + asf(lo & 0xffff0000u);
    float pg = a[2] + asf(hi << 16);
    float po = a[3] + asf(hi & 0xffff0000u);
    float ei = __builtin_amdgcn_exp2f(-fmaxf(pi, -40.f));   // e^-i
    float ef = __builtin_amdgcn_exp2f(-fmaxf(pf, -40.f));   // e^-f
    float eo = __builtin_amdgcn_exp2f(-fmaxf(po, -40.f));   // e^-o
    float ug = __builtin_amdgcn_exp2f(fminf(pg, 40.f));     // e^{2g}
    float A  = 1.f + ei, Bv = 1.f + ug, C = 1.f + ef;
    float AB  = A * Bv;
    float num = fmaf(Bv - 2.f, C, cc * AB);
    float cn  = num * __builtin_amdgcn_rcpf(C * AB);
    cc = cn;
    float uc = __builtin_amdgcn_exp2f(fminf(cn * 2.8853900817779268f, 40.f));
    float h  = (uc - 1.f) * __builtin_amdgcn_rcpf((uc + 1.f) * (1.f + eo));
    uint_t pk = __builtin_amdgcn_cvt_pk_fp8_f32(h, h, 0, false);
    return (uchar_t)(pk & 0xFF);
}

// ---------------- K3: recurrence, 64 WGs = 2 dirs x 32 batch-groups ---------
// (unchanged R11 structure; only change: MFMA C-input fed from a
// loop-invariant zero vector -> no per-step acc zero-init movs)
__global__ __launch_bounds__(512, 2) void lstm_k(const ushort_t* __restrict__ xg,
                                                 const uchar_t* __restrict__ whh8,
                                                 uchar_t* __restrict__ hhist8) {
    const int d  = blockIdx.x >> 5;             // direction
    const int bg = blockIdx.x & 31;             // batch group (2 batches)
    const int tid = threadIdx.x;
    const int w = tid >> 6, lane = tid & 63;
    const int q = lane >> 4, m16 = lane & 15;
    const int hu   = w * 32 + (lane >> 1);      // epilogue hidden unit
    const int bloc = lane & 1;                  // local batch 0..1
    const int blg  = bg * 2 + bloc;             // global batch

    __shared__ uchar_t hb8[2][16 * HPAD];       // fp8 h, [local batch][hu]
    __shared__ float   accT[2048];              // 8KB gate-quads [hu][b]
    for (int i = tid; i < 2 * 16 * HPAD; i += 512) ((uchar_t*)hb8)[i] = 0;

    const uchar_t* wp = whh8 + (size_t)(d * NG + w * 128) * NH;
    v8i wreg[8][2];
    #pragma unroll
    for (int mt = 0; mt < 8; ++mt)
        #pragma unroll
        for (int kh = 0; kh < 2; ++kh)
            wreg[mt][kh] = *(const v8i*)(wp + (size_t)(mt * 16 + m16) * NH + kh * 128 + q * 32);
    #pragma unroll
    for (int mt = 0; mt < 8; ++mt)
        #pragma unroll
        for (int kh = 0; kh < 2; ++kh)
            asm volatile("" : "+a"(wreg[mt][kh]));   // pin in AGPR class

    float cc = 0.f;
    __syncthreads();

    const int scl = 0x7f7f7f7f;                 // e8m0 scale = 1.0 in all bytes
    const ushort_t* xb_ = xg + (size_t)d * NG + hu * 4;

    ull_t xw, xwn;
    {
        const int t0 = d ? (NT - 1) : 0;
        xw = *(const ull_t*)(xb_ + (size_t)(t0 * NB + blg) * NCC);
    }
    floatx4 z4 = (floatx4){0.f, 0.f, 0.f, 0.f};
    asm volatile("" : "+v"(z4));                // keep live, loop-invariant

    #pragma unroll 1
    for (int s = 0; s < NT; ++s) {
        const int t = d ? (NT - 1 - s) : s;

        if (s + 1 < NT) {
            const int tn = d ? (NT - 2 - s) : (s + 1);
            xwn = *(const ull_t*)(xb_ + (size_t)(tn * NB + blg) * NCC);
        }

        const uchar_t* hrow = &hb8[s & 1][m16 * HPAD];
        v8i hf0 = *(const v8i*)(hrow + q * 32);
        v8i hf1 = *(const v8i*)(hrow + 128 + q * 32);

        floatx4 acc[8];
        #pragma unroll
        for (int mt = 0; mt < 8; ++mt)
            acc[mt] = __builtin_amdgcn_mfma_scale_f32_16x16x128_f8f6f4(
                wreg[mt][0], hf0, z4, 0, 0, 0, scl, 0, scl);
        #pragma unroll
        for (int mt = 0; mt < 8; ++mt)
            acc[mt] = __builtin_amdgcn_mfma_scale_f32_16x16x128_f8f6f4(
                wreg[mt][1], hf1, acc[mt], 0, 0, 0, scl, 0, scl);

        if (m16 < 2) {
            #pragma unroll
            for (int mt = 0; mt < 8; ++mt) {
                int hu_w = w * 32 + mt * 4 + q;
                *(floatx4*)((uchar_t*)accT + (size_t)hu_w * 32 + m16 * 16) = acc[mt];
            }
        }
        __syncthreads();                        // accT complete

        floatx4 a = *(const floatx4*)((const uchar_t*)accT + (size_t)hu * 32 + bloc * 16);
        uchar_t hv = lstm_gate(a, xw, cc);
        hb8[(s + 1) & 1][bloc * HPAD + hu] = hv;

        xw = xwn;
        __syncthreads();                        // h(s+1) complete

        if (tid < 64) {
            int b_ = tid >> 5, off = (tid & 31) * 8;
            ull_t v = *(const ull_t*)(&hb8[(s + 1) & 1][b_ * HPAD + off]);
            *(ull_t*)(hhist8 + ((size_t)(d * NT + t) * NB + bg * 2 + b_) * NH + off) = v;
        }
    }
}

// ---------------- K4: em[t,b,l] = feats . W_lin[l] + b_lin ------------------
__global__ void em_k(const uchar_t* __restrict__ hhist8, const float* __restrict__ Wlin,
                     const float* __restrict__ blin, float* __restrict__ em) {
    const int t = blockIdx.x;
    const int tid = threadIdx.x;          // 576 threads
    __shared__ float Ws[NL * 520];
    for (int idx = tid; idx < NL * 2 * NH; idx += 576) {
        int l = idx >> 9, k = idx & 511;
        Ws[l * 520 + k] = Wlin[l * 2 * NH + k];
    }
    __syncthreads();
    const int b = tid / NL, l = tid - b * NL;
    const uchar_t* hf = hhist8 + ((size_t)t * NB + b) * NH;
    const uchar_t* hb = hhist8 + ((size_t)(NT + t) * NB + b) * NH;
    float acc = blin[l];
    #pragma unroll 4
    for (int kc = 0; kc < NH / 4; ++kc) {
        uint_t u = *(const uint_t*)(hf + kc * 4);
        floatx2 p0 = __builtin_amdgcn_cvt_pk_f32_fp8(u, false);
        floatx2 p1 = __builtin_amdgcn_cvt_pk_f32_fp8(u, true);
        acc += p0.x * Ws[l * 520 + kc * 4]     + p0.y * Ws[l * 520 + kc * 4 + 1]
             + p1.x * Ws[l * 520 + kc * 4 + 2] + p1.y * Ws[l * 520 + kc * 4 + 3];
    }
    #pragma unroll 4
    for (int kc = 0; kc < NH / 4; ++kc) {
        uint_t u = *(const uint_t*)(hb + kc * 4);
        floatx2 p0 = __builtin_amdgcn_cvt_pk_f32_fp8(u, false);
        floatx2 p1 = __builtin_amdgcn_cvt_pk_f32_fp8(u, true);
        acc += p0.x * Ws[l * 520 + NH + kc * 4]     + p0.y * Ws[l * 520 + NH + kc * 4 + 1]
             + p1.x * Ws[l * 520 + NH + kc * 4 + 2] + p1.y * Ws[l * 520 + NH + kc * 4 + 3];
    }
    em[((size_t)t * NB + b) * NL + l] = acc;
}

// ---------------- K5: CRF numerator per batch (parallel over t) -------------
__global__ void num_k(const float* __restrict__ em, const int* __restrict__ mask,
                      const int* __restrict__ labels, const float* __restrict__ start,
                      const float* __restrict__ endt, const float* __restrict__ trans,
                      float* __restrict__ numbuf) {
    const int b = blockIdx.x;       // 64 blocks x 64 threads (1 wave)
    const int lane = threadIdx.x;
    int cntm = 0;
    for (int t = lane; t < NT; t += 64) cntm += (mask[b * NT + t] != 0);
    #pragma unroll
    for (int off = 32; off > 0; off >>= 1) cntm += __shfl_down(cntm, off);
    const int len = __shfl(cntm, 0);

    float part = 0.f;
    for (int t = lane; t < NT; t += 64) {
        if (t >= 1 && t < len) {
            int tp = labels[b * NT + t - 1];
            int tg = labels[b * NT + t];
            part += trans[tp * NL + tg] + em[((size_t)t * NB + b) * NL + tg];
        }
    }
    #pragma unroll
    for (int off = 32; off > 0; off >>= 1) part += __shfl_down(part, off);
    if (lane == 0) {
        int tag0 = labels[b * NT];
        numbuf[b] = part + start[tag0] + em[(size_t)b * NL + tag0]
                  + endt[labels[b * NT + len - 1]];
    }
}

// ---------------- K6: CRF forward (logZ), diff = logZ - num -----------------
__global__ void crf_k(const float* __restrict__ em, const int* __restrict__ mask,
                      const float* __restrict__ start, const float* __restrict__ endt,
                      const float* __restrict__ trans, const float* __restrict__ numbuf,
                      float* __restrict__ diff) {
    const int b = blockIdx.x;
    const int lane = threadIdx.x;       // 64 threads = 1 wave
    int cnt = 0;
    for (int t = lane; t < NT; t += 64) cnt += (mask[b * NT + t] != 0);
    #pragma unroll
    for (int off = 32; off > 0; off >>= 1) cnt += __shfl_down(cnt, off);
    const int len = __shfl(cnt, 0);

    float tcol[NL];
    #pragma unroll
    for (int i = 0; i < NL; ++i) tcol[i] = (lane < NL) ? trans[i * NL + lane] : 0.f;
    float endv = (lane < NL) ? endt[lane] : 0.f;
    float score = (lane < NL) ? start[lane] + em[(size_t)b * NL + lane] : -1e30f;

    for (int t = 1; t < len; ++t) {
        float emv = (lane < NL) ? em[((size_t)t * NB + b) * NL + lane] : 0.f;
        float sv[NL];
        #pragma unroll
        for (int i = 0; i < NL; ++i) sv[i] = __shfl(score, i) + tcol[i];
        float m = sv[0];
        #pragma unroll
        for (int i = 1; i < NL; ++i) m = fmaxf(m, sv[i]);
        float sum = 0.f;
        #pragma unroll
        for (int i = 0; i < NL; ++i) sum += __expf(sv[i] - m);
        float nxt = m + __logf(sum) + emv;
        if (lane < NL) score = nxt;
    }
    float v = (lane < NL) ? score + endv : -1e30f;
    float m = -1e30f;
    float sv[NL];
    #pragma unroll
    for (int i = 0; i < NL; ++i) { sv[i] = __shfl(v, i); m = fmaxf(m, sv[i]); }
    float sum = 0.f;
    #pragma unroll
    for (int i = 0; i < NL; ++i) sum += __expf(sv[i] - m);
    float logZ = m + __logf(sum);
    if (lane == 0) diff[b] = logZ - numbuf[b];
}

// ---------------- K7: mean over batch -> d_out ------------------------------
__global__ void final_k(const float* __restrict__ diff, float* __restrict__ out) {
    float v = diff[threadIdx.x];
    #pragma unroll
    for (int off = 32; off > 0; off >>= 1) v += __shfl_down(v, off);
    if (threadIdx.x == 0) out[0] = v * (1.0f / NB);
}

extern "C" void kernel_launch(void* const* d_in, const int* in_sizes, int n_in,
                              void* d_out, int out_size, void* d_ws, size_t ws_size,
                              hipStream_t stream) {
    const float* emb   = (const float*)d_in[0];
    const float* Wihf  = (const float*)d_in[1];
    const float* Whhf  = (const float*)d_in[2];
    const float* bf    = (const float*)d_in[3];
    const float* Wihb  = (const float*)d_in[4];
    const float* Whhb  = (const float*)d_in[5];
    const float* bb    = (const float*)d_in[6];
    const float* Wlin  = (const float*)d_in[7];
    const float* blin  = (const float*)d_in[8];
    const float* start = (const float*)d_in[9];
    const float* endt  = (const float*)d_in[10];
    const float* trans = (const float*)d_in[11];
    const int*   mask  = (const int*)d_in[12];
    const int*   labels= (const int*)d_in[13];

    char* ws = (char*)d_ws;
    ushort_t* xbf   = (ushort_t*)(ws + 0);                     // 50,331,648
    ushort_t* wcat  = (ushort_t*)(ws + 50331648);              //  3,145,728
    uchar_t*  whh8  = (uchar_t*) (ws + 53477376);              //    524,288
    float*    bias  = (float*)   (ws + 54001664);              //      8,192
    ushort_t* xg    = (ushort_t*)(ws + 54009856);              // 134,217,728
    uchar_t*  hh8   = (uchar_t*) (ws + 188227584);             // 16,777,216
    float*    em    = (float*)   (ws + 205004800);             //  1,179,648
    float*    numb  = (float*)   (ws + 206184448);             //        256
    float*    diff  = (float*)   (ws + 206184704);             //        256

    conv_x<<<NT * NB * (NE / 4) / 256, 256, 0, stream>>>(emb, xbf);
    conv_w<<<(NCC * NE + NCC * NH / 2 + NCC) / 256, 256, 0, stream>>>(
        Wihf, Wihb, Whhf, Whhb, bf, bb, wcat, whh8, bias);
    gemm_xg<<<dim3(NCC / 128, NT * NB / 128), 256, 0, stream>>>(xbf, wcat, bias, xg);
    lstm_k<<<64, 512, 0, stream>>>(xg, whh8, hh8);
    em_k<<<NT, 576, 0, stream>>>(hh8, Wlin, blin, em);
    num_k<<<NB, 64, 0, stream>>>(em, mask, labels, start, endt, trans, numb);
    crf_k<<<NB, 64, 0, stream>>>(em, mask, start, endt, trans, numb, diff);
    final_k<<<1, 64, 0, stream>>>(diff, (float*)d_out);
}

// Round 10
// 1059.505 us; speedup vs baseline: 1.0268x; 1.0268x over previous
//
#include <hip/hip_runtime.h>
#include <hip/hip_bf16.h>
#include <cstdint>
#include <cstddef>

// B=64 T=512 E=768 H=256 L=9.  BiLSTM + linear + CRF loglik (scalar out).
// R13: fix R12's gemm_xg regression.  R12 removed LDS padding for
// global_load_lds and thereby installed a 16-way read bank-conflict
// (row stride 128B -> all 16 lanes of each ds_read_b128 column-slice on
// the same 4 banks, ~5.7x).  Per guide Rule #21 (both-sides-or-neither):
// keep LDS dest linear (HW requirement), PRE-SWIZZLE the global source
// (chunk (row,kc) loads global slot kc^(row&7)) and compensate on the
// read (slot = (ks*4+q) ^ (m16&7)).  Reads become 2-way (free); staging
// keeps the width-16 direct HBM->LDS path.  lstm_k unchanged.

typedef __attribute__((ext_vector_type(8))) short short8;
typedef __attribute__((ext_vector_type(4))) float floatx4;
typedef __attribute__((ext_vector_type(2))) float floatx2;
typedef __attribute__((ext_vector_type(8))) int v8i;
typedef unsigned short ushort_t;
typedef unsigned char uchar_t;
typedef unsigned int uint_t;
typedef unsigned long long ull_t;

#define NB   64
#define NT   512
#define NE   768
#define NH   256
#define NL   9
#define NG   1024   // 4*H
#define NCC  2048   // both dirs' gates
#define HPAD 272    // LDS h row stride (bytes, fp8)

__device__ inline float asf(uint_t u) {
    union { uint_t i; float f; } v; v.i = u; return v.f;
}
__device__ inline ushort_t f2b(float f) {
    union { float f; uint_t i; } v; v.f = f;
    uint_t r = (v.i + 0x7FFFu + ((v.i >> 16) & 1u)) >> 16;
    return (ushort_t)r;
}

// Direct HBM->LDS 16B async copy (emits global_load_lds_dwordx4).
__device__ inline void g2lds16(const void* g, void* l) {
    __builtin_amdgcn_global_load_lds(
        (const __attribute__((address_space(1))) uint_t*)g,
        (__attribute__((address_space(3))) uint_t*)l, 16, 0, 0);
}

// ---------------- K1: embeddings (B,T,E) f32 -> xbf (T,B,E) bf16 ------------
__global__ void conv_x(const float* __restrict__ emb, ushort_t* __restrict__ xbf) {
    int id = blockIdx.x * blockDim.x + threadIdx.x;      // over T*B*(E/4)
    int t  = id / (NB * (NE / 4));
    int rm = id - t * (NB * (NE / 4));
    int b  = rm / (NE / 4);
    int e4 = rm - b * (NE / 4);
    const float4 v = *(const float4*)(emb + ((size_t)b * NT + t) * NE + e4 * 4);
    ushort_t o[4] = { f2b(v.x), f2b(v.y), f2b(v.z), f2b(v.w) };
    *(uint2*)(xbf + ((size_t)t * NB + b) * NE + e4 * 4) = *(const uint2*)o;
}

// ---------------- K1b: weights. Row interleave: row' = d*1024 + hu*4 + gate -
// Rows prescaled: i,f,o by log2(e); g by 2*log2(e)  (log2-domain gates).
__global__ void conv_w(const float* __restrict__ Wihf, const float* __restrict__ Wihb,
                       const float* __restrict__ Whhf, const float* __restrict__ Whhb,
                       const float* __restrict__ bf,   const float* __restrict__ bb,
                       ushort_t* __restrict__ wcat, uchar_t* __restrict__ whh8,
                       float* __restrict__ bias) {
    int idx = blockIdx.x * blockDim.x + threadIdx.x;
    const int NW1 = NCC * NE;            // 1572864
    const int NW2 = NCC * NH / 2;        // 262144 fp8 pairs
    const float SC1 = 1.4426950408889634f;
    const float SC2 = 2.8853900817779268f;
    if (idx < NW1) {
        int rowp = idx / NE, col = idx - rowp * NE;
        int d = rowp >> 10, rr = rowp & 1023;
        int hu = rr >> 2, gate = rr & 3;
        float sc = (gate == 2) ? SC2 : SC1;
        const float* W = d ? Wihb : Wihf;
        wcat[idx] = f2b(W[(size_t)(gate * NH + hu) * NE + col] * sc);
    } else if (idx < NW1 + NW2) {
        int j = idx - NW1;
        int rowp = j >> 7, kp = (j & 127) * 2;
        int d = rowp >> 10, rr = rowp & 1023;
        int hu = rr >> 2, gate = rr & 3;
        float sc = (gate == 2) ? SC2 : SC1;
        const float* W = d ? Whhb : Whhf;
        float f0 = W[(size_t)(gate * NH + hu) * NH + kp] * sc;
        float f1 = W[(size_t)(gate * NH + hu) * NH + kp + 1] * sc;
        uint_t pk = __builtin_amdgcn_cvt_pk_fp8_f32(f0, f1, 0, false);
        *(ushort_t*)(whh8 + (size_t)rowp * NH + kp) = (ushort_t)(pk & 0xFFFF);
    } else if (idx < NW1 + NW2 + NCC) {
        int rowp = idx - NW1 - NW2;
        int d = rowp >> 10, rr = rowp & 1023;
        int hu = rr >> 2, gate = rr & 3;
        float sc = (gate == 2) ? SC2 : SC1;
        bias[rowp] = (d ? bb : bf)[gate * NH + hu] * sc;
    }
}

// ---------------- K2: xg = xbf(32768x768) @ wcat^T(2048x768) + bias ---------
// global_load_lds width=16 staging with pre-swizzled global source
// (slot kc^(row&7)); reads compensate with slot ^ (m16&7) -> 2-way (free).
__global__ __launch_bounds__(256) void gemm_xg(const ushort_t* __restrict__ A,
                                               const ushort_t* __restrict__ W,
                                               const float* __restrict__ bias,
                                               ushort_t* __restrict__ C) {
    __shared__ __align__(16) ushort_t As[128 * 64];
    __shared__ __align__(16) ushort_t Bs[128 * 64];
    const int tid = threadIdx.x;
    const int wave = tid >> 6, lane = tid & 63;
    const int q = lane >> 4, m16 = lane & 15;
    const int wm = wave & 1, wn = wave >> 1;
    const int m0 = blockIdx.y * 128, n0 = blockIdx.x * 128;

    floatx4 acc[4][4];
    #pragma unroll
    for (int i = 0; i < 4; ++i)
        #pragma unroll
        for (int j = 0; j < 4; ++j) acc[i][j] = (floatx4){0.f, 0.f, 0.f, 0.f};

    for (int kt = 0; kt < NE / 64; ++kt) {
        __syncthreads();
        // Stage: LDS dest linear (chunk*16); global source slot pre-swizzled.
        #pragma unroll
        for (int it = 0; it < 4; ++it) {
            int chunk = tid + it * 256;         // 0..1023
            int row = chunk >> 3, kc = chunk & 7;
            int kcs = kc ^ (row & 7);           // involution on slot bits
            g2lds16(A + (size_t)(m0 + row) * NE + kt * 64 + kcs * 8,
                    (uchar_t*)As + chunk * 16);
            g2lds16(W + (size_t)(n0 + row) * NE + kt * 64 + kcs * 8,
                    (uchar_t*)Bs + chunk * 16);
        }
        __syncthreads();                        // implicit vmcnt(0) drain
        #pragma unroll
        for (int ks = 0; ks < 2; ++ks) {
            short8 af[4], bfr[4];
            #pragma unroll
            for (int mt = 0; mt < 4; ++mt) {
                int row = wm * 64 + mt * 16 + m16;
                int slot = (ks * 4 + q) ^ (m16 & 7);
                af[mt] = *(const short8*)((const uchar_t*)As + row * 128 + slot * 16);
            }
            #pragma unroll
            for (int nt = 0; nt < 4; ++nt) {
                int row = wn * 64 + nt * 16 + m16;
                int slot = (ks * 4 + q) ^ (m16 & 7);
                bfr[nt] = *(const short8*)((const uchar_t*)Bs + row * 128 + slot * 16);
            }
            #pragma unroll
            for (int mt = 0; mt < 4; ++mt)
                #pragma unroll
                for (int nt = 0; nt < 4; ++nt)
                    acc[mt][nt] = __builtin_amdgcn_mfma_f32_16x16x32_bf16(
                        af[mt], bfr[nt], acc[mt][nt], 0, 0, 0);
        }
    }
    float bcol[4];
    #pragma unroll
    for (int nt = 0; nt < 4; ++nt) bcol[nt] = bias[n0 + wn * 64 + nt * 16 + m16];
    #pragma unroll
    for (int mt = 0; mt < 4; ++mt)
        #pragma unroll
        for (int nt = 0; nt < 4; ++nt) {
            int gn = n0 + wn * 64 + nt * 16 + m16;
            #pragma unroll
            for (int r = 0; r < 4; ++r) {
                int gm = m0 + wm * 64 + mt * 16 + q * 4 + r;
                C[(size_t)gm * NCC + gn] = f2b(acc[mt][nt][r] + bcol[nt]);
            }
        }
}

// ---------------- scalar log2-domain LSTM gate (verified R8) ----------------
__device__ inline uchar_t lstm_gate(floatx4 a, ull_t xr, float& cc) {
    uint_t lo = (uint_t)xr, hi = (uint_t)(xr >> 32);
    float pi = a[0] + asf(lo << 16);
    float pf = a[1] + asf(lo & 0xffff0000u);
    float pg = a[2] + asf(hi << 16);
    float po = a[3] + asf(hi & 0xffff0000u);
    float ei = __builtin_amdgcn_exp2f(-fmaxf(pi, -40.f));   // e^-i
    float ef = __builtin_amdgcn_exp2f(-fmaxf(pf, -40.f));   // e^-f
    float eo = __builtin_amdgcn_exp2f(-fmaxf(po, -40.f));   // e^-o
    float ug = __builtin_amdgcn_exp2f(fminf(pg, 40.f));     // e^{2g}
    float A  = 1.f + ei, Bv = 1.f + ug, C = 1.f + ef;
    float AB  = A * Bv;
    float num = fmaf(Bv - 2.f, C, cc * AB);
    float cn  = num * __builtin_amdgcn_rcpf(C * AB);
    cc = cn;
    float uc = __builtin_amdgcn_exp2f(fminf(cn * 2.8853900817779268f, 40.f));
    float h  = (uc - 1.f) * __builtin_amdgcn_rcpf((uc + 1.f) * (1.f + eo));
    uint_t pk = __builtin_amdgcn_cvt_pk_fp8_f32(h, h, 0, false);
    return (uchar_t)(pk & 0xFF);
}

// ---------------- K3: recurrence, 64 WGs = 2 dirs x 32 batch-groups ---------
__global__ __launch_bounds__(512, 2) void lstm_k(const ushort_t* __restrict__ xg,
                                                 const uchar_t* __restrict__ whh8,
                                                 uchar_t* __restrict__ hhist8) {
    const int d  = blockIdx.x >> 5;             // direction
    const int bg = blockIdx.x & 31;             // batch group (2 batches)
    const int tid = threadIdx.x;
    const int w = tid >> 6, lane = tid & 63;
    const int q = lane >> 4, m16 = lane & 15;
    const int hu   = w * 32 + (lane >> 1);      // epilogue hidden unit
    const int bloc = lane & 1;                  // local batch 0..1
    const int blg  = bg * 2 + bloc;             // global batch

    __shared__ uchar_t hb8[2][16 * HPAD];       // fp8 h, [local batch][hu]
    __shared__ float   accT[2048];              // 8KB gate-quads [hu][b]
    for (int i = tid; i < 2 * 16 * HPAD; i += 512) ((uchar_t*)hb8)[i] = 0;

    const uchar_t* wp = whh8 + (size_t)(d * NG + w * 128) * NH;
    v8i wreg[8][2];
    #pragma unroll
    for (int mt = 0; mt < 8; ++mt)
        #pragma unroll
        for (int kh = 0; kh < 2; ++kh)
            wreg[mt][kh] = *(const v8i*)(wp + (size_t)(mt * 16 + m16) * NH + kh * 128 + q * 32);
    #pragma unroll
    for (int mt = 0; mt < 8; ++mt)
        #pragma unroll
        for (int kh = 0; kh < 2; ++kh)
            asm volatile("" : "+a"(wreg[mt][kh]));   // pin in AGPR class

    float cc = 0.f;
    __syncthreads();

    const int scl = 0x7f7f7f7f;                 // e8m0 scale = 1.0 in all bytes
    const ushort_t* xb_ = xg + (size_t)d * NG + hu * 4;

    ull_t xw, xwn;
    {
        const int t0 = d ? (NT - 1) : 0;
        xw = *(const ull_t*)(xb_ + (size_t)(t0 * NB + blg) * NCC);
    }
    floatx4 z4 = (floatx4){0.f, 0.f, 0.f, 0.f};
    asm volatile("" : "+v"(z4));                // keep live, loop-invariant

    #pragma unroll 1
    for (int s = 0; s < NT; ++s) {
        const int t = d ? (NT - 1 - s) : s;

        if (s + 1 < NT) {
            const int tn = d ? (NT - 2 - s) : (s + 1);
            xwn = *(const ull_t*)(xb_ + (size_t)(tn * NB + blg) * NCC);
        }

        const uchar_t* hrow = &hb8[s & 1][m16 * HPAD];
        v8i hf0 = *(const v8i*)(hrow + q * 32);
        v8i hf1 = *(const v8i*)(hrow + 128 + q * 32);

        floatx4 acc[8];
        #pragma unroll
        for (int mt = 0; mt < 8; ++mt)
            acc[mt] = __builtin_amdgcn_mfma_scale_f32_16x16x128_f8f6f4(
                wreg[mt][0], hf0, z4, 0, 0, 0, scl, 0, scl);
        #pragma unroll
        for (int mt = 0; mt < 8; ++mt)
            acc[mt] = __builtin_amdgcn_mfma_scale_f32_16x16x128_f8f6f4(
                wreg[mt][1], hf1, acc[mt], 0, 0, 0, scl, 0, scl);

        if (m16 < 2) {
            #pragma unroll
            for (int mt = 0; mt < 8; ++mt) {
                int hu_w = w * 32 + mt * 4 + q;
                *(floatx4*)((uchar_t*)accT + (size_t)hu_w * 32 + m16 * 16) = acc[mt];
            }
        }
        __syncthreads();                        // accT complete

        floatx4 a = *(const floatx4*)((const uchar_t*)accT + (size_t)hu * 32 + bloc * 16);
        uchar_t hv = lstm_gate(a, xw, cc);
        hb8[(s + 1) & 1][bloc * HPAD + hu] = hv;

        xw = xwn;
        __syncthreads();                        // h(s+1) complete

        if (tid < 64) {
            int b_ = tid >> 5, off = (tid & 31) * 8;
            ull_t v = *(const ull_t*)(&hb8[(s + 1) & 1][b_ * HPAD + off]);
            *(ull_t*)(hhist8 + ((size_t)(d * NT + t) * NB + bg * 2 + b_) * NH + off) = v;
        }
    }
}

// ---------------- K4: em[t,b,l] = feats . W_lin[l] + b_lin ------------------
__global__ void em_k(const uchar_t* __restrict__ hhist8, const float* __restrict__ Wlin,
                     const float* __restrict__ blin, float* __restrict__ em) {
    const int t = blockIdx.x;
    const int tid = threadIdx.x;          // 576 threads
    __shared__ float Ws[NL * 520];
    for (int idx = tid; idx < NL * 2 * NH; idx += 576) {
        int l = idx >> 9, k = idx & 511;
        Ws[l * 520 + k] = Wlin[l * 2 * NH + k];
    }
    __syncthreads();
    const int b = tid / NL, l = tid - b * NL;
    const uchar_t* hf = hhist8 + ((size_t)t * NB + b) * NH;
    const uchar_t* hb = hhist8 + ((size_t)(NT + t) * NB + b) * NH;
    float acc = blin[l];
    #pragma unroll 4
    for (int kc = 0; kc < NH / 4; ++kc) {
        uint_t u = *(const uint_t*)(hf + kc * 4);
        floatx2 p0 = __builtin_amdgcn_cvt_pk_f32_fp8(u, false);
        floatx2 p1 = __builtin_amdgcn_cvt_pk_f32_fp8(u, true);
        acc += p0.x * Ws[l * 520 + kc * 4]     + p0.y * Ws[l * 520 + kc * 4 + 1]
             + p1.x * Ws[l * 520 + kc * 4 + 2] + p1.y * Ws[l * 520 + kc * 4 + 3];
    }
    #pragma unroll 4
    for (int kc = 0; kc < NH / 4; ++kc) {
        uint_t u = *(const uint_t*)(hb + kc * 4);
        floatx2 p0 = __builtin_amdgcn_cvt_pk_f32_fp8(u, false);
        floatx2 p1 = __builtin_amdgcn_cvt_pk_f32_fp8(u, true);
        acc += p0.x * Ws[l * 520 + NH + kc * 4]     + p0.y * Ws[l * 520 + NH + kc * 4 + 1]
             + p1.x * Ws[l * 520 + NH + kc * 4 + 2] + p1.y * Ws[l * 520 + NH + kc * 4 + 3];
    }
    em[((size_t)t * NB + b) * NL + l] = acc;
}

// ---------------- K5: CRF numerator per batch (parallel over t) -------------
__global__ void num_k(const float* __restrict__ em, const int* __restrict__ mask,
                      const int* __restrict__ labels, const float* __restrict__ start,
                      const float* __restrict__ endt, const float* __restrict__ trans,
                      float* __restrict__ numbuf) {
    const int b = blockIdx.x;       // 64 blocks x 64 threads (1 wave)
    const int lane = threadIdx.x;
    int cntm = 0;
    for (int t = lane; t < NT; t += 64) cntm += (mask[b * NT + t] != 0);
    #pragma unroll
    for (int off = 32; off > 0; off >>= 1) cntm += __shfl_down(cntm, off);
    const int len = __shfl(cntm, 0);

    float part = 0.f;
    for (int t = lane; t < NT; t += 64) {
        if (t >= 1 && t < len) {
            int tp = labels[b * NT + t - 1];
            int tg = labels[b * NT + t];
            part += trans[tp * NL + tg] + em[((size_t)t * NB + b) * NL + tg];
        }
    }
    #pragma unroll
    for (int off = 32; off > 0; off >>= 1) part += __shfl_down(part, off);
    if (lane == 0) {
        int tag0 = labels[b * NT];
        numbuf[b] = part + start[tag0] + em[(size_t)b * NL + tag0]
                  + endt[labels[b * NT + len - 1]];
    }
}

// ---------------- K6: CRF forward (logZ), diff = logZ - num -----------------
__global__ void crf_k(const float* __restrict__ em, const int* __restrict__ mask,
                      const float* __restrict__ start, const float* __restrict__ endt,
                      const float* __restrict__ trans, const float* __restrict__ numbuf,
                      float* __restrict__ diff) {
    const int b = blockIdx.x;
    const int lane = threadIdx.x;       // 64 threads = 1 wave
    int cnt = 0;
    for (int t = lane; t < NT; t += 64) cnt += (mask[b * NT + t] != 0);
    #pragma unroll
    for (int off = 32; off > 0; off >>= 1) cnt += __shfl_down(cnt, off);
    const int len = __shfl(cnt, 0);

    float tcol[NL];
    #pragma unroll
    for (int i = 0; i < NL; ++i) tcol[i] = (lane < NL) ? trans[i * NL + lane] : 0.f;
    float endv = (lane < NL) ? endt[lane] : 0.f;
    float score = (lane < NL) ? start[lane] + em[(size_t)b * NL + lane] : -1e30f;

    for (int t = 1; t < len; ++t) {
        float emv = (lane < NL) ? em[((size_t)t * NB + b) * NL + lane] : 0.f;
        float sv[NL];
        #pragma unroll
        for (int i = 0; i < NL; ++i) sv[i] = __shfl(score, i) + tcol[i];
        float m = sv[0];
        #pragma unroll
        for (int i = 1; i < NL; ++i) m = fmaxf(m, sv[i]);
        float sum = 0.f;
        #pragma unroll
        for (int i = 0; i < NL; ++i) sum += __expf(sv[i] - m);
        float nxt = m + __logf(sum) + emv;
        if (lane < NL) score = nxt;
    }
    float v = (lane < NL) ? score + endv : -1e30f;
    float m = -1e30f;
    float sv[NL];
    #pragma unroll
    for (int i = 0; i < NL; ++i) { sv[i] = __shfl(v, i); m = fmaxf(m, sv[i]); }
    float sum = 0.f;
    #pragma unroll
    for (int i = 0; i < NL; ++i) sum += __expf(sv[i] - m);
    float logZ = m + __logf(sum);
    if (lane == 0) diff[b] = logZ - numbuf[b];
}

// ---------------- K7: mean over batch -> d_out ------------------------------
__global__ void final_k(const float* __restrict__ diff, float* __restrict__ out) {
    float v = diff[threadIdx.x];
    #pragma unroll
    for (int off = 32; off > 0; off >>= 1) v += __shfl_down(v, off);
    if (threadIdx.x == 0) out[0] = v * (1.0f / NB);
}

extern "C" void kernel_launch(void* const* d_in, const int* in_sizes, int n_in,
                              void* d_out, int out_size, void* d_ws, size_t ws_size,
                              hipStream_t stream) {
    const float* emb   = (const float*)d_in[0];
    const float* Wihf  = (const float*)d_in[1];
    const float* Whhf  = (const float*)d_in[2];
    const float* bf    = (const float*)d_in[3];
    const float* Wihb  = (const float*)d_in[4];
    const float* Whhb  = (const float*)d_in[5];
    const float* bb    = (const float*)d_in[6];
    const float* Wlin  = (const float*)d_in[7];
    const float* blin  = (const float*)d_in[8];
    const float* start = (const float*)d_in[9];
    const float* endt  = (const float*)d_in[10];
    const float* trans = (const float*)d_in[11];
    const int*   mask  = (const int*)d_in[12];
    const int*   labels= (const int*)d_in[13];

    char* ws = (char*)d_ws;
    ushort_t* xbf   = (ushort_t*)(ws + 0);                     // 50,331,648
    ushort_t* wcat  = (ushort_t*)(ws + 50331648);              //  3,145,728
    uchar_t*  whh8  = (uchar_t*) (ws + 53477376);              //    524,288
    float*    bias  = (float*)   (ws + 54001664);              //      8,192
    ushort_t* xg    = (ushort_t*)(ws + 54009856);              // 134,217,728
    uchar_t*  hh8   = (uchar_t*) (ws + 188227584);             // 16,777,216
    float*    em    = (float*)   (ws + 205004800);             //  1,179,648
    float*    numb  = (float*)   (ws + 206184448);             //        256
    float*    diff  = (float*)   (ws + 206184704);             //        256

    conv_x<<<NT * NB * (NE / 4) / 256, 256, 0, stream>>>(emb, xbf);
    conv_w<<<(NCC * NE + NCC * NH / 2 + NCC) / 256, 256, 0, stream>>>(
        Wihf, Wihb, Whhf, Whhb, bf, bb, wcat, whh8, bias);
    gemm_xg<<<dim3(NCC / 128, NT * NB / 128), 256, 0, stream>>>(xbf, wcat, bias, xg);
    lstm_k<<<64, 512, 0, stream>>>(xg, whh8, hh8);
    em_k<<<NT, 576, 0, stream>>>(hh8, Wlin, blin, em);
    num_k<<<NB, 64, 0, stream>>>(em, mask, labels, start, endt, trans, numb);
    crf_k<<<NB, 64, 0, stream>>>(em, mask, start, endt, trans, numb, diff);
    final_k<<<1, 64, 0, stream>>>(diff, (float*)d_out);
}

// Round 11
// 990.116 us; speedup vs baseline: 1.0987x; 1.0701x over previous
//
#include <hip/hip_runtime.h>
#include <hip/hip_bf16.h>
#include <cstdint>
#include <cstddef>

// B=64 T=512 E=768 H=256 L=9.  BiLSTM + linear + CRF loglik (scalar out).
// R14: gemm_xg switched to fp8-MX (e4m3 inputs, mfma_scale 16x16x128 unit
// scales -- the instruction already verified in lstm_k).  bf16 gemm at this
// shape is ~320TF (m102 curve) = ~330us; fp8 halves traffic, halves
// k-iterations (6 vs 12 barrier drains) and ~2x the MFMA rate.  Bank
// discipline per R13: pre-swizzled global slot ^(row&7), reads as two b128
// halves at slot (2q+h)^(m16&7) -> 2-way (free).  + XCD-aware block swizzle
// (bijective, 4096%8=0): each XCD owns 32 contiguous m-panels -> A-tile L2
// reuse x16.  conv_x/conv_w emit fp8 for the gemm inputs; xg output stays
// bf16.  lstm_k and tail kernels unchanged.

typedef __attribute__((ext_vector_type(8))) short short8;
typedef __attribute__((ext_vector_type(4))) float floatx4;
typedef __attribute__((ext_vector_type(2))) float floatx2;
typedef __attribute__((ext_vector_type(8))) int v8i;
typedef unsigned short ushort_t;
typedef unsigned char uchar_t;
typedef unsigned int uint_t;
typedef unsigned long long ull_t;

#define NB   64
#define NT   512
#define NE   768
#define NH   256
#define NL   9
#define NG   1024   // 4*H
#define NCC  2048   // both dirs' gates
#define HPAD 272    // LDS h row stride (bytes, fp8)

__device__ inline float asf(uint_t u) {
    union { uint_t i; float f; } v; v.i = u; return v.f;
}
__device__ inline ushort_t f2b(float f) {
    union { float f; uint_t i; } v; v.f = f;
    uint_t r = (v.i + 0x7FFFu + ((v.i >> 16) & 1u)) >> 16;
    return (ushort_t)r;
}

// Direct HBM->LDS 16B async copy (emits global_load_lds_dwordx4).
__device__ inline void g2lds16(const void* g, void* l) {
    __builtin_amdgcn_global_load_lds(
        (const __attribute__((address_space(1))) uint_t*)g,
        (__attribute__((address_space(3))) uint_t*)l, 16, 0, 0);
}

// ---------------- K1: embeddings (B,T,E) f32 -> xbf8 (T,B,E) fp8 ------------
__global__ void conv_x(const float* __restrict__ emb, uchar_t* __restrict__ xbf8) {
    int id = blockIdx.x * blockDim.x + threadIdx.x;      // over T*B*(E/4)
    int t  = id / (NB * (NE / 4));
    int rm = id - t * (NB * (NE / 4));
    int b  = rm / (NE / 4);
    int e4 = rm - b * (NE / 4);
    const float4 v = *(const float4*)(emb + ((size_t)b * NT + t) * NE + e4 * 4);
    uint_t p = __builtin_amdgcn_cvt_pk_fp8_f32(v.x, v.y, 0, false);
    p = __builtin_amdgcn_cvt_pk_fp8_f32(v.z, v.w, p, true);
    *(uint_t*)(xbf8 + ((size_t)t * NB + b) * NE + e4 * 4) = p;
}

// ---------------- K1b: weights. Row interleave: row' = d*1024 + hu*4 + gate -
// Rows prescaled: i,f,o by log2(e); g by 2*log2(e)  (log2-domain gates).
// W_ih now packed fp8 (2 cols/thread), W_hh fp8 as before, bias f32.
__global__ void conv_w(const float* __restrict__ Wihf, const float* __restrict__ Wihb,
                       const float* __restrict__ Whhf, const float* __restrict__ Whhb,
                       const float* __restrict__ bf,   const float* __restrict__ bb,
                       uchar_t* __restrict__ wcat8, uchar_t* __restrict__ whh8,
                       float* __restrict__ bias) {
    int idx = blockIdx.x * blockDim.x + threadIdx.x;
    const int NW1 = NCC * NE / 2;        // 786432 fp8 pairs (W_ih)
    const int NW2 = NCC * NH / 2;        // 262144 fp8 pairs (W_hh)
    const float SC1 = 1.4426950408889634f;
    const float SC2 = 2.8853900817779268f;
    if (idx < NW1) {
        int rowp = idx / (NE / 2), cp = (idx - rowp * (NE / 2)) * 2;
        int d = rowp >> 10, rr = rowp & 1023;
        int hu = rr >> 2, gate = rr & 3;
        float sc = (gate == 2) ? SC2 : SC1;
        const float* W = d ? Wihb : Wihf;
        float f0 = W[(size_t)(gate * NH + hu) * NE + cp] * sc;
        float f1 = W[(size_t)(gate * NH + hu) * NE + cp + 1] * sc;
        uint_t pk = __builtin_amdgcn_cvt_pk_fp8_f32(f0, f1, 0, false);
        *(ushort_t*)(wcat8 + (size_t)rowp * NE + cp) = (ushort_t)(pk & 0xFFFF);
    } else if (idx < NW1 + NW2) {
        int j = idx - NW1;
        int rowp = j >> 7, kp = (j & 127) * 2;
        int d = rowp >> 10, rr = rowp & 1023;
        int hu = rr >> 2, gate = rr & 3;
        float sc = (gate == 2) ? SC2 : SC1;
        const float* W = d ? Whhb : Whhf;
        float f0 = W[(size_t)(gate * NH + hu) * NH + kp] * sc;
        float f1 = W[(size_t)(gate * NH + hu) * NH + kp + 1] * sc;
        uint_t pk = __builtin_amdgcn_cvt_pk_fp8_f32(f0, f1, 0, false);
        *(ushort_t*)(whh8 + (size_t)rowp * NH + kp) = (ushort_t)(pk & 0xFFFF);
    } else if (idx < NW1 + NW2 + NCC) {
        int rowp = idx - NW1 - NW2;
        int d = rowp >> 10, rr = rowp & 1023;
        int hu = rr >> 2, gate = rr & 3;
        float sc = (gate == 2) ? SC2 : SC1;
        bias[rowp] = (d ? bb : bf)[gate * NH + hu] * sc;
    }
}

// ---------------- K2: xg = xbf8(32768x768) @ wcat8^T(2048x768) + bias -------
// fp8-MX mfma_scale 16x16x128 (unit scales), 6 k-tiles of 128.  LDS dest
// linear for global_load_lds; global source slot pre-swizzled ^(row&7);
// fragment reads = two b128 halves at slots (2q+h)^(m16&7) -> 2-way (free).
// XCD-aware block swizzle: flat' = (flat%8)*512 + flat/8 (bijective).
__global__ __launch_bounds__(256) void gemm_xg(const uchar_t* __restrict__ A,
                                               const uchar_t* __restrict__ W,
                                               const float* __restrict__ bias,
                                               ushort_t* __restrict__ C) {
    __shared__ __align__(16) uchar_t As[128 * 128];
    __shared__ __align__(16) uchar_t Bs[128 * 128];
    const int tid = threadIdx.x;
    const int wave = tid >> 6, lane = tid & 63;
    const int q = lane >> 4, m16 = lane & 15;
    const int wm = wave & 1, wn = wave >> 1;
    int flat = blockIdx.y * 16 + blockIdx.x;
    int fs = (flat & 7) * 512 + (flat >> 3);     // XCD-chunked remap
    const int m0 = (fs >> 4) * 128, n0 = (fs & 15) * 128;

    floatx4 acc[4][4];
    #pragma unroll
    for (int i = 0; i < 4; ++i)
        #pragma unroll
        for (int j = 0; j < 4; ++j) acc[i][j] = (floatx4){0.f, 0.f, 0.f, 0.f};

    const int scl = 0x7f7f7f7f;                 // e8m0 unit scales
    union V8U { v8i v; uint4 u[2]; };

    for (int kt = 0; kt < NE / 128; ++kt) {     // 6 k-tiles
        __syncthreads();
        #pragma unroll
        for (int it = 0; it < 4; ++it) {
            int chunk = tid + it * 256;         // 0..1023 (1024 x 16B = 16KB)
            int row = chunk >> 3, sn = chunk & 7;
            int ss = sn ^ (row & 7);            // involution on slot bits
            g2lds16(A + (size_t)(m0 + row) * NE + kt * 128 + ss * 16,
                    As + chunk * 16);
            g2lds16(W + (size_t)(n0 + row) * NE + kt * 128 + ss * 16,
                    Bs + chunk * 16);
        }
        __syncthreads();                        // implicit vmcnt(0) drain

        v8i af[4], bfr[4];
        const int s0 = (2 * q) ^ (m16 & 7), s1 = (2 * q + 1) ^ (m16 & 7);
        #pragma unroll
        for (int mt = 0; mt < 4; ++mt) {
            int row = wm * 64 + mt * 16 + m16;
            V8U t;
            t.u[0] = *(const uint4*)(As + row * 128 + s0 * 16);
            t.u[1] = *(const uint4*)(As + row * 128 + s1 * 16);
            af[mt] = t.v;
        }
        #pragma unroll
        for (int nt = 0; nt < 4; ++nt) {
            int row = wn * 64 + nt * 16 + m16;
            V8U t;
            t.u[0] = *(const uint4*)(Bs + row * 128 + s0 * 16);
            t.u[1] = *(const uint4*)(Bs + row * 128 + s1 * 16);
            bfr[nt] = t.v;
        }
        #pragma unroll
        for (int mt = 0; mt < 4; ++mt)
            #pragma unroll
            for (int nt = 0; nt < 4; ++nt)
                acc[mt][nt] = __builtin_amdgcn_mfma_scale_f32_16x16x128_f8f6f4(
                    af[mt], bfr[nt], acc[mt][nt], 0, 0, 0, scl, 0, scl);
    }
    float bcol[4];
    #pragma unroll
    for (int nt = 0; nt < 4; ++nt) bcol[nt] = bias[n0 + wn * 64 + nt * 16 + m16];
    #pragma unroll
    for (int mt = 0; mt < 4; ++mt)
        #pragma unroll
        for (int nt = 0; nt < 4; ++nt) {
            int gn = n0 + wn * 64 + nt * 16 + m16;
            #pragma unroll
            for (int r = 0; r < 4; ++r) {
                int gm = m0 + wm * 64 + mt * 16 + q * 4 + r;
                C[(size_t)gm * NCC + gn] = f2b(acc[mt][nt][r] + bcol[nt]);
            }
        }
}

// ---------------- scalar log2-domain LSTM gate (verified R8) ----------------
__device__ inline uchar_t lstm_gate(floatx4 a, ull_t xr, float& cc) {
    uint_t lo = (uint_t)xr, hi = (uint_t)(xr >> 32);
    float pi = a[0] + asf(lo << 16);
    float pf = a[1] + asf(lo & 0xffff0000u);
    float pg = a[2] + asf(hi << 16);
    float po = a[3] + asf(hi & 0xffff0000u);
    float ei = __builtin_amdgcn_exp2f(-fmaxf(pi, -40.f));   // e^-i
    float ef = __builtin_amdgcn_exp2f(-fmaxf(pf, -40.f));   // e^-f
    float eo = __builtin_amdgcn_exp2f(-fmaxf(po, -40.f));   // e^-o
    float ug = __builtin_amdgcn_exp2f(fminf(pg, 40.f));     // e^{2g}
    float A  = 1.f + ei, Bv = 1.f + ug, C = 1.f + ef;
    float AB  = A * Bv;
    float num = fmaf(Bv - 2.f, C, cc * AB);
    float cn  = num * __builtin_amdgcn_rcpf(C * AB);
    cc = cn;
    float uc = __builtin_amdgcn_exp2f(fminf(cn * 2.8853900817779268f, 40.f));
    float h  = (uc - 1.f) * __builtin_amdgcn_rcpf((uc + 1.f) * (1.f + eo));
    uint_t pk = __builtin_amdgcn_cvt_pk_fp8_f32(h, h, 0, false);
    return (uchar_t)(pk & 0xFF);
}

// ---------------- K3: recurrence, 64 WGs = 2 dirs x 32 batch-groups ---------
__global__ __launch_bounds__(512, 2) void lstm_k(const ushort_t* __restrict__ xg,
                                                 const uchar_t* __restrict__ whh8,
                                                 uchar_t* __restrict__ hhist8) {
    const int d  = blockIdx.x >> 5;             // direction
    const int bg = blockIdx.x & 31;             // batch group (2 batches)
    const int tid = threadIdx.x;
    const int w = tid >> 6, lane = tid & 63;
    const int q = lane >> 4, m16 = lane & 15;
    const int hu   = w * 32 + (lane >> 1);      // epilogue hidden unit
    const int bloc = lane & 1;                  // local batch 0..1
    const int blg  = bg * 2 + bloc;             // global batch

    __shared__ uchar_t hb8[2][16 * HPAD];       // fp8 h, [local batch][hu]
    __shared__ float   accT[2048];              // 8KB gate-quads [hu][b]
    for (int i = tid; i < 2 * 16 * HPAD; i += 512) ((uchar_t*)hb8)[i] = 0;

    const uchar_t* wp = whh8 + (size_t)(d * NG + w * 128) * NH;
    v8i wreg[8][2];
    #pragma unroll
    for (int mt = 0; mt < 8; ++mt)
        #pragma unroll
        for (int kh = 0; kh < 2; ++kh)
            wreg[mt][kh] = *(const v8i*)(wp + (size_t)(mt * 16 + m16) * NH + kh * 128 + q * 32);
    #pragma unroll
    for (int mt = 0; mt < 8; ++mt)
        #pragma unroll
        for (int kh = 0; kh < 2; ++kh)
            asm volatile("" : "+a"(wreg[mt][kh]));   // pin in AGPR class

    float cc = 0.f;
    __syncthreads();

    const int scl = 0x7f7f7f7f;                 // e8m0 scale = 1.0 in all bytes
    const ushort_t* xb_ = xg + (size_t)d * NG + hu * 4;

    ull_t xw, xwn;
    {
        const int t0 = d ? (NT - 1) : 0;
        xw = *(const ull_t*)(xb_ + (size_t)(t0 * NB + blg) * NCC);
    }
    floatx4 z4 = (floatx4){0.f, 0.f, 0.f, 0.f};
    asm volatile("" : "+v"(z4));                // keep live, loop-invariant

    #pragma unroll 1
    for (int s = 0; s < NT; ++s) {
        const int t = d ? (NT - 1 - s) : s;

        if (s + 1 < NT) {
            const int tn = d ? (NT - 2 - s) : (s + 1);
            xwn = *(const ull_t*)(xb_ + (size_t)(tn * NB + blg) * NCC);
        }

        const uchar_t* hrow = &hb8[s & 1][m16 * HPAD];
        v8i hf0 = *(const v8i*)(hrow + q * 32);
        v8i hf1 = *(const v8i*)(hrow + 128 + q * 32);

        floatx4 acc[8];
        #pragma unroll
        for (int mt = 0; mt < 8; ++mt)
            acc[mt] = __builtin_amdgcn_mfma_scale_f32_16x16x128_f8f6f4(
                wreg[mt][0], hf0, z4, 0, 0, 0, scl, 0, scl);
        #pragma unroll
        for (int mt = 0; mt < 8; ++mt)
            acc[mt] = __builtin_amdgcn_mfma_scale_f32_16x16x128_f8f6f4(
                wreg[mt][1], hf1, acc[mt], 0, 0, 0, scl, 0, scl);

        if (m16 < 2) {
            #pragma unroll
            for (int mt = 0; mt < 8; ++mt) {
                int hu_w = w * 32 + mt * 4 + q;
                *(floatx4*)((uchar_t*)accT + (size_t)hu_w * 32 + m16 * 16) = acc[mt];
            }
        }
        __syncthreads();                        // accT complete

        floatx4 a = *(const floatx4*)((const uchar_t*)accT + (size_t)hu * 32 + bloc * 16);
        uchar_t hv = lstm_gate(a, xw, cc);
        hb8[(s + 1) & 1][bloc * HPAD + hu] = hv;

        xw = xwn;
        __syncthreads();                        // h(s+1) complete

        if (tid < 64) {
            int b_ = tid >> 5, off = (tid & 31) * 8;
            ull_t v = *(const ull_t*)(&hb8[(s + 1) & 1][b_ * HPAD + off]);
            *(ull_t*)(hhist8 + ((size_t)(d * NT + t) * NB + bg * 2 + b_) * NH + off) = v;
        }
    }
}

// ---------------- K4: em[t,b,l] = feats . W_lin[l] + b_lin ------------------
__global__ void em_k(const uchar_t* __restrict__ hhist8, const float* __restrict__ Wlin,
                     const float* __restrict__ blin, float* __restrict__ em) {
    const int t = blockIdx.x;
    const int tid = threadIdx.x;          // 576 threads
    __shared__ float Ws[NL * 520];
    for (int idx = tid; idx < NL * 2 * NH; idx += 576) {
        int l = idx >> 9, k = idx & 511;
        Ws[l * 520 + k] = Wlin[l * 2 * NH + k];
    }
    __syncthreads();
    const int b = tid / NL, l = tid - b * NL;
    const uchar_t* hf = hhist8 + ((size_t)t * NB + b) * NH;
    const uchar_t* hb = hhist8 + ((size_t)(NT + t) * NB + b) * NH;
    float acc = blin[l];
    #pragma unroll 4
    for (int kc = 0; kc < NH / 4; ++kc) {
        uint_t u = *(const uint_t*)(hf + kc * 4);
        floatx2 p0 = __builtin_amdgcn_cvt_pk_f32_fp8(u, false);
        floatx2 p1 = __builtin_amdgcn_cvt_pk_f32_fp8(u, true);
        acc += p0.x * Ws[l * 520 + kc * 4]     + p0.y * Ws[l * 520 + kc * 4 + 1]
             + p1.x * Ws[l * 520 + kc * 4 + 2] + p1.y * Ws[l * 520 + kc * 4 + 3];
    }
    #pragma unroll 4
    for (int kc = 0; kc < NH / 4; ++kc) {
        uint_t u = *(const uint_t*)(hb + kc * 4);
        floatx2 p0 = __builtin_amdgcn_cvt_pk_f32_fp8(u, false);
        floatx2 p1 = __builtin_amdgcn_cvt_pk_f32_fp8(u, true);
        acc += p0.x * Ws[l * 520 + NH + kc * 4]     + p0.y * Ws[l * 520 + NH + kc * 4 + 1]
             + p1.x * Ws[l * 520 + NH + kc * 4 + 2] + p1.y * Ws[l * 520 + NH + kc * 4 + 3];
    }
    em[((size_t)t * NB + b) * NL + l] = acc;
}

// ---------------- K5: CRF numerator per batch (parallel over t) -------------
__global__ void num_k(const float* __restrict__ em, const int* __restrict__ mask,
                      const int* __restrict__ labels, const float* __restrict__ start,
                      const float* __restrict__ endt, const float* __restrict__ trans,
                      float* __restrict__ numbuf) {
    const int b = blockIdx.x;       // 64 blocks x 64 threads (1 wave)
    const int lane = threadIdx.x;
    int cntm = 0;
    for (int t = lane; t < NT; t += 64) cntm += (mask[b * NT + t] != 0);
    #pragma unroll
    for (int off = 32; off > 0; off >>= 1) cntm += __shfl_down(cntm, off);
    const int len = __shfl(cntm, 0);

    float part = 0.f;
    for (int t = lane; t < NT; t += 64) {
        if (t >= 1 && t < len) {
            int tp = labels[b * NT + t - 1];
            int tg = labels[b * NT + t];
            part += trans[tp * NL + tg] + em[((size_t)t * NB + b) * NL + tg];
        }
    }
    #pragma unroll
    for (int off = 32; off > 0; off >>= 1) part += __shfl_down(part, off);
    if (lane == 0) {
        int tag0 = labels[b * NT];
        numbuf[b] = part + start[tag0] + em[(size_t)b * NL + tag0]
                  + endt[labels[b * NT + len - 1]];
    }
}

// ---------------- K6: CRF forward (logZ), diff = logZ - num -----------------
__global__ void crf_k(const float* __restrict__ em, const int* __restrict__ mask,
                      const float* __restrict__ start, const float* __restrict__ endt,
                      const float* __restrict__ trans, const float* __restrict__ numbuf,
                      float* __restrict__ diff) {
    const int b = blockIdx.x;
    const int lane = threadIdx.x;       // 64 threads = 1 wave
    int cnt = 0;
    for (int t = lane; t < NT; t += 64) cnt += (mask[b * NT + t] != 0);
    #pragma unroll
    for (int off = 32; off > 0; off >>= 1) cnt += __shfl_down(cnt, off);
    const int len = __shfl(cnt, 0);

    float tcol[NL];
    #pragma unroll
    for (int i = 0; i < NL; ++i) tcol[i] = (lane < NL) ? trans[i * NL + lane] : 0.f;
    float endv = (lane < NL) ? endt[lane] : 0.f;
    float score = (lane < NL) ? start[lane] + em[(size_t)b * NL + lane] : -1e30f;

    for (int t = 1; t < len; ++t) {
        float emv = (lane < NL) ? em[((size_t)t * NB + b) * NL + lane] : 0.f;
        float sv[NL];
        #pragma unroll
        for (int i = 0; i < NL; ++i) sv[i] = __shfl(score, i) + tcol[i];
        float m = sv[0];
        #pragma unroll
        for (int i = 1; i < NL; ++i) m = fmaxf(m, sv[i]);
        float sum = 0.f;
        #pragma unroll
        for (int i = 0; i < NL; ++i) sum += __expf(sv[i] - m);
        float nxt = m + __logf(sum) + emv;
        if (lane < NL) score = nxt;
    }
    float v = (lane < NL) ? score + endv : -1e30f;
    float m = -1e30f;
    float sv[NL];
    #pragma unroll
    for (int i = 0; i < NL; ++i) { sv[i] = __shfl(v, i); m = fmaxf(m, sv[i]); }
    float sum = 0.f;
    #pragma unroll
    for (int i = 0; i < NL; ++i) sum += __expf(sv[i] - m);
    float logZ = m + __logf(sum);
    if (lane == 0) diff[b] = logZ - numbuf[b];
}

// ---------------- K7: mean over batch -> d_out ------------------------------
__global__ void final_k(const float* __restrict__ diff, float* __restrict__ out) {
    float v = diff[threadIdx.x];
    #pragma unroll
    for (int off = 32; off > 0; off >>= 1) v += __shfl_down(v, off);
    if (threadIdx.x == 0) out[0] = v * (1.0f / NB);
}

extern "C" void kernel_launch(void* const* d_in, const int* in_sizes, int n_in,
                              void* d_out, int out_size, void* d_ws, size_t ws_size,
                              hipStream_t stream) {
    const float* emb   = (const float*)d_in[0];
    const float* Wihf  = (const float*)d_in[1];
    const float* Whhf  = (const float*)d_in[2];
    const float* bf    = (const float*)d_in[3];
    const float* Wihb  = (const float*)d_in[4];
    const float* Whhb  = (const float*)d_in[5];
    const float* bb    = (const float*)d_in[6];
    const float* Wlin  = (const float*)d_in[7];
    const float* blin  = (const float*)d_in[8];
    const float* start = (const float*)d_in[9];
    const float* endt  = (const float*)d_in[10];
    const float* trans = (const float*)d_in[11];
    const int*   mask  = (const int*)d_in[12];
    const int*   labels= (const int*)d_in[13];

    char* ws = (char*)d_ws;
    uchar_t*  xbf8  = (uchar_t*) (ws + 0);                     // 25,165,824
    uchar_t*  wcat8 = (uchar_t*) (ws + 50331648);              //  1,572,864
    uchar_t*  whh8  = (uchar_t*) (ws + 53477376);              //    524,288
    float*    bias  = (float*)   (ws + 54001664);              //      8,192
    ushort_t* xg    = (ushort_t*)(ws + 54009856);              // 134,217,728
    uchar_t*  hh8   = (uchar_t*) (ws + 188227584);             // 16,777,216
    float*    em    = (float*)   (ws + 205004800);             //  1,179,648
    float*    numb  = (float*)   (ws + 206184448);             //        256
    float*    diff  = (float*)   (ws + 206184704);             //        256

    conv_x<<<NT * NB * (NE / 4) / 256, 256, 0, stream>>>(emb, xbf8);
    conv_w<<<(NCC * NE / 2 + NCC * NH / 2 + NCC) / 256, 256, 0, stream>>>(
        Wihf, Wihb, Whhf, Whhb, bf, bb, wcat8, whh8, bias);
    gemm_xg<<<dim3(NCC / 128, NT * NB / 128), 256, 0, stream>>>(xbf8, wcat8, bias, xg);
    lstm_k<<<64, 512, 0, stream>>>(xg, whh8, hh8);
    em_k<<<NT, 576, 0, stream>>>(hh8, Wlin, blin, em);
    num_k<<<NB, 64, 0, stream>>>(em, mask, labels, start, endt, trans, numb);
    crf_k<<<NB, 64, 0, stream>>>(em, mask, start, endt, trans, numb, diff);
    final_k<<<1, 64, 0, stream>>>(diff, (float*)d_out);
}

// Round 12
// 965.875 us; speedup vs baseline: 1.1263x; 1.0251x over previous
//
#include <hip/hip_runtime.h>
#include <hip/hip_bf16.h>
#include <cstdint>
#include <cstddef>

// B=64 T=512 E=768 H=256 L=9.  BiLSTM + linear + CRF loglik (scalar out).
// R15: lstm_k barrier #1 removed.  The accT transpose is WAVE-LOCAL (wave w
// writes accT rows [w*32,w*32+32) and only wave w's epilogue reads them), so
// a workgroup barrier is unnecessary -- s_waitcnt lgkmcnt(0) + sched_barrier
// suffices for cross-lane intra-wave LDS ordering.  This deletes one
// full-drain sync per step AND lets the 2 waves/SIMD phase-stagger (wave A's
// gate VALU under wave B's MFMA).  Barrier #2 stays (h is WG-shared).
// Everything else identical to R14 (fp8-MX gemm + XCD swizzle, verified).

typedef __attribute__((ext_vector_type(8))) short short8;
typedef __attribute__((ext_vector_type(4))) float floatx4;
typedef __attribute__((ext_vector_type(2))) float floatx2;
typedef __attribute__((ext_vector_type(8))) int v8i;
typedef unsigned short ushort_t;
typedef unsigned char uchar_t;
typedef unsigned int uint_t;
typedef unsigned long long ull_t;

#define NB   64
#define NT   512
#define NE   768
#define NH   256
#define NL   9
#define NG   1024   // 4*H
#define NCC  2048   // both dirs' gates
#define HPAD 272    // LDS h row stride (bytes, fp8)

__device__ inline float asf(uint_t u) {
    union { uint_t i; float f; } v; v.i = u; return v.f;
}
__device__ inline ushort_t f2b(float f) {
    union { float f; uint_t i; } v; v.f = f;
    uint_t r = (v.i + 0x7FFFu + ((v.i >> 16) & 1u)) >> 16;
    return (ushort_t)r;
}

// Direct HBM->LDS 16B async copy (emits global_load_lds_dwordx4).
__device__ inline void g2lds16(const void* g, void* l) {
    __builtin_amdgcn_global_load_lds(
        (const __attribute__((address_space(1))) uint_t*)g,
        (__attribute__((address_space(3))) uint_t*)l, 16, 0, 0);
}

// ---------------- K1: embeddings (B,T,E) f32 -> xbf8 (T,B,E) fp8 ------------
__global__ void conv_x(const float* __restrict__ emb, uchar_t* __restrict__ xbf8) {
    int id = blockIdx.x * blockDim.x + threadIdx.x;      // over T*B*(E/4)
    int t  = id / (NB * (NE / 4));
    int rm = id - t * (NB * (NE / 4));
    int b  = rm / (NE / 4);
    int e4 = rm - b * (NE / 4);
    const float4 v = *(const float4*)(emb + ((size_t)b * NT + t) * NE + e4 * 4);
    uint_t p = __builtin_amdgcn_cvt_pk_fp8_f32(v.x, v.y, 0, false);
    p = __builtin_amdgcn_cvt_pk_fp8_f32(v.z, v.w, p, true);
    *(uint_t*)(xbf8 + ((size_t)t * NB + b) * NE + e4 * 4) = p;
}

// ---------------- K1b: weights. Row interleave: row' = d*1024 + hu*4 + gate -
// Rows prescaled: i,f,o by log2(e); g by 2*log2(e)  (log2-domain gates).
__global__ void conv_w(const float* __restrict__ Wihf, const float* __restrict__ Wihb,
                       const float* __restrict__ Whhf, const float* __restrict__ Whhb,
                       const float* __restrict__ bf,   const float* __restrict__ bb,
                       uchar_t* __restrict__ wcat8, uchar_t* __restrict__ whh8,
                       float* __restrict__ bias) {
    int idx = blockIdx.x * blockDim.x + threadIdx.x;
    const int NW1 = NCC * NE / 2;        // 786432 fp8 pairs (W_ih)
    const int NW2 = NCC * NH / 2;        // 262144 fp8 pairs (W_hh)
    const float SC1 = 1.4426950408889634f;
    const float SC2 = 2.8853900817779268f;
    if (idx < NW1) {
        int rowp = idx / (NE / 2), cp = (idx - rowp * (NE / 2)) * 2;
        int d = rowp >> 10, rr = rowp & 1023;
        int hu = rr >> 2, gate = rr & 3;
        float sc = (gate == 2) ? SC2 : SC1;
        const float* W = d ? Wihb : Wihf;
        float f0 = W[(size_t)(gate * NH + hu) * NE + cp] * sc;
        float f1 = W[(size_t)(gate * NH + hu) * NE + cp + 1] * sc;
        uint_t pk = __builtin_amdgcn_cvt_pk_fp8_f32(f0, f1, 0, false);
        *(ushort_t*)(wcat8 + (size_t)rowp * NE + cp) = (ushort_t)(pk & 0xFFFF);
    } else if (idx < NW1 + NW2) {
        int j = idx - NW1;
        int rowp = j >> 7, kp = (j & 127) * 2;
        int d = rowp >> 10, rr = rowp & 1023;
        int hu = rr >> 2, gate = rr & 3;
        float sc = (gate == 2) ? SC2 : SC1;
        const float* W = d ? Whhb : Whhf;
        float f0 = W[(size_t)(gate * NH + hu) * NH + kp] * sc;
        float f1 = W[(size_t)(gate * NH + hu) * NH + kp + 1] * sc;
        uint_t pk = __builtin_amdgcn_cvt_pk_fp8_f32(f0, f1, 0, false);
        *(ushort_t*)(whh8 + (size_t)rowp * NH + kp) = (ushort_t)(pk & 0xFFFF);
    } else if (idx < NW1 + NW2 + NCC) {
        int rowp = idx - NW1 - NW2;
        int d = rowp >> 10, rr = rowp & 1023;
        int hu = rr >> 2, gate = rr & 3;
        float sc = (gate == 2) ? SC2 : SC1;
        bias[rowp] = (d ? bb : bf)[gate * NH + hu] * sc;
    }
}

// ---------------- K2: xg = xbf8(32768x768) @ wcat8^T(2048x768) + bias -------
// fp8-MX mfma_scale 16x16x128 (unit scales), 6 k-tiles of 128.  LDS dest
// linear for global_load_lds; global source slot pre-swizzled ^(row&7);
// fragment reads = two b128 halves at slots (2q+h)^(m16&7) -> 2-way (free).
// XCD-aware block swizzle: flat' = (flat%8)*512 + flat/8 (bijective).
__global__ __launch_bounds__(256) void gemm_xg(const uchar_t* __restrict__ A,
                                               const uchar_t* __restrict__ W,
                                               const float* __restrict__ bias,
                                               ushort_t* __restrict__ C) {
    __shared__ __align__(16) uchar_t As[128 * 128];
    __shared__ __align__(16) uchar_t Bs[128 * 128];
    const int tid = threadIdx.x;
    const int wave = tid >> 6, lane = tid & 63;
    const int q = lane >> 4, m16 = lane & 15;
    const int wm = wave & 1, wn = wave >> 1;
    int flat = blockIdx.y * 16 + blockIdx.x;
    int fs = (flat & 7) * 512 + (flat >> 3);     // XCD-chunked remap
    const int m0 = (fs >> 4) * 128, n0 = (fs & 15) * 128;

    floatx4 acc[4][4];
    #pragma unroll
    for (int i = 0; i < 4; ++i)
        #pragma unroll
        for (int j = 0; j < 4; ++j) acc[i][j] = (floatx4){0.f, 0.f, 0.f, 0.f};

    const int scl = 0x7f7f7f7f;                 // e8m0 unit scales
    union V8U { v8i v; uint4 u[2]; };

    for (int kt = 0; kt < NE / 128; ++kt) {     // 6 k-tiles
        __syncthreads();
        #pragma unroll
        for (int it = 0; it < 4; ++it) {
            int chunk = tid + it * 256;         // 0..1023 (1024 x 16B = 16KB)
            int row = chunk >> 3, sn = chunk & 7;
            int ss = sn ^ (row & 7);            // involution on slot bits
            g2lds16(A + (size_t)(m0 + row) * NE + kt * 128 + ss * 16,
                    As + chunk * 16);
            g2lds16(W + (size_t)(n0 + row) * NE + kt * 128 + ss * 16,
                    Bs + chunk * 16);
        }
        __syncthreads();                        // implicit vmcnt(0) drain

        v8i af[4], bfr[4];
        const int s0 = (2 * q) ^ (m16 & 7), s1 = (2 * q + 1) ^ (m16 & 7);
        #pragma unroll
        for (int mt = 0; mt < 4; ++mt) {
            int row = wm * 64 + mt * 16 + m16;
            V8U t;
            t.u[0] = *(const uint4*)(As + row * 128 + s0 * 16);
            t.u[1] = *(const uint4*)(As + row * 128 + s1 * 16);
            af[mt] = t.v;
        }
        #pragma unroll
        for (int nt = 0; nt < 4; ++nt) {
            int row = wn * 64 + nt * 16 + m16;
            V8U t;
            t.u[0] = *(const uint4*)(Bs + row * 128 + s0 * 16);
            t.u[1] = *(const uint4*)(Bs + row * 128 + s1 * 16);
            bfr[nt] = t.v;
        }
        #pragma unroll
        for (int mt = 0; mt < 4; ++mt)
            #pragma unroll
            for (int nt = 0; nt < 4; ++nt)
                acc[mt][nt] = __builtin_amdgcn_mfma_scale_f32_16x16x128_f8f6f4(
                    af[mt], bfr[nt], acc[mt][nt], 0, 0, 0, scl, 0, scl);
    }
    float bcol[4];
    #pragma unroll
    for (int nt = 0; nt < 4; ++nt) bcol[nt] = bias[n0 + wn * 64 + nt * 16 + m16];
    #pragma unroll
    for (int mt = 0; mt < 4; ++mt)
        #pragma unroll
        for (int nt = 0; nt < 4; ++nt) {
            int gn = n0 + wn * 64 + nt * 16 + m16;
            #pragma unroll
            for (int r = 0; r < 4; ++r) {
                int gm = m0 + wm * 64 + mt * 16 + q * 4 + r;
                C[(size_t)gm * NCC + gn] = f2b(acc[mt][nt][r] + bcol[nt]);
            }
        }
}

// ---------------- scalar log2-domain LSTM gate (verified R8) ----------------
__device__ inline uchar_t lstm_gate(floatx4 a, ull_t xr, float& cc) {
    uint_t lo = (uint_t)xr, hi = (uint_t)(xr >> 32);
    float pi = a[0] + asf(lo << 16);
    float pf = a[1] + asf(lo & 0xffff0000u);
    float pg = a[2] + asf(hi << 16);
    float po = a[3] + asf(hi & 0xffff0000u);
    float ei = __builtin_amdgcn_exp2f(-fmaxf(pi, -40.f));   // e^-i
    float ef = __builtin_amdgcn_exp2f(-fmaxf(pf, -40.f));   // e^-f
    float eo = __builtin_amdgcn_exp2f(-fmaxf(po, -40.f));   // e^-o
    float ug = __builtin_amdgcn_exp2f(fminf(pg, 40.f));     // e^{2g}
    float A  = 1.f + ei, Bv = 1.f + ug, C = 1.f + ef;
    float AB  = A * Bv;
    float num = fmaf(Bv - 2.f, C, cc * AB);
    float cn  = num * __builtin_amdgcn_rcpf(C * AB);
    cc = cn;
    float uc = __builtin_amdgcn_exp2f(fminf(cn * 2.8853900817779268f, 40.f));
    float h  = (uc - 1.f) * __builtin_amdgcn_rcpf((uc + 1.f) * (1.f + eo));
    uint_t pk = __builtin_amdgcn_cvt_pk_fp8_f32(h, h, 0, false);
    return (uchar_t)(pk & 0xFF);
}

// ---------------- K3: recurrence, 64 WGs = 2 dirs x 32 batch-groups ---------
// 2 batches/WG.  accT transpose is wave-local: lgkmcnt(0) instead of a
// barrier; one __syncthreads per step (h complete).
__global__ __launch_bounds__(512, 2) void lstm_k(const ushort_t* __restrict__ xg,
                                                 const uchar_t* __restrict__ whh8,
                                                 uchar_t* __restrict__ hhist8) {
    const int d  = blockIdx.x >> 5;             // direction
    const int bg = blockIdx.x & 31;             // batch group (2 batches)
    const int tid = threadIdx.x;
    const int w = tid >> 6, lane = tid & 63;
    const int q = lane >> 4, m16 = lane & 15;
    const int hu   = w * 32 + (lane >> 1);      // epilogue hidden unit
    const int bloc = lane & 1;                  // local batch 0..1
    const int blg  = bg * 2 + bloc;             // global batch

    __shared__ uchar_t hb8[2][16 * HPAD];       // fp8 h, [local batch][hu]
    __shared__ float   accT[2048];              // 8KB gate-quads [hu][b]
    for (int i = tid; i < 2 * 16 * HPAD; i += 512) ((uchar_t*)hb8)[i] = 0;

    const uchar_t* wp = whh8 + (size_t)(d * NG + w * 128) * NH;
    v8i wreg[8][2];
    #pragma unroll
    for (int mt = 0; mt < 8; ++mt)
        #pragma unroll
        for (int kh = 0; kh < 2; ++kh)
            wreg[mt][kh] = *(const v8i*)(wp + (size_t)(mt * 16 + m16) * NH + kh * 128 + q * 32);
    #pragma unroll
    for (int mt = 0; mt < 8; ++mt)
        #pragma unroll
        for (int kh = 0; kh < 2; ++kh)
            asm volatile("" : "+a"(wreg[mt][kh]));   // pin in AGPR class

    float cc = 0.f;
    __syncthreads();

    const int scl = 0x7f7f7f7f;                 // e8m0 scale = 1.0 in all bytes
    const ushort_t* xb_ = xg + (size_t)d * NG + hu * 4;

    ull_t xw, xwn;
    {
        const int t0 = d ? (NT - 1) : 0;
        xw = *(const ull_t*)(xb_ + (size_t)(t0 * NB + blg) * NCC);
    }
    floatx4 z4 = (floatx4){0.f, 0.f, 0.f, 0.f};
    asm volatile("" : "+v"(z4));                // keep live, loop-invariant

    #pragma unroll 1
    for (int s = 0; s < NT; ++s) {
        const int t = d ? (NT - 1 - s) : s;

        if (s + 1 < NT) {
            const int tn = d ? (NT - 2 - s) : (s + 1);
            xwn = *(const ull_t*)(xb_ + (size_t)(tn * NB + blg) * NCC);
        }

        const uchar_t* hrow = &hb8[s & 1][m16 * HPAD];
        v8i hf0 = *(const v8i*)(hrow + q * 32);
        v8i hf1 = *(const v8i*)(hrow + 128 + q * 32);

        floatx4 acc[8];
        #pragma unroll
        for (int mt = 0; mt < 8; ++mt)
            acc[mt] = __builtin_amdgcn_mfma_scale_f32_16x16x128_f8f6f4(
                wreg[mt][0], hf0, z4, 0, 0, 0, scl, 0, scl);
        #pragma unroll
        for (int mt = 0; mt < 8; ++mt)
            acc[mt] = __builtin_amdgcn_mfma_scale_f32_16x16x128_f8f6f4(
                wreg[mt][1], hf1, acc[mt], 0, 0, 0, scl, 0, scl);

        // acc transpose: WAVE-LOCAL.  Wave w writes rows [w*32,w*32+32) and
        // only wave w reads them -> intra-wave LDS ordering suffices.
        if (m16 < 2) {
            #pragma unroll
            for (int mt = 0; mt < 8; ++mt) {
                int hu_w = w * 32 + mt * 4 + q;
                *(floatx4*)((uchar_t*)accT + (size_t)hu_w * 32 + m16 * 16) = acc[mt];
            }
        }
        asm volatile("s_waitcnt lgkmcnt(0)" ::: "memory");   // writes retired
        __builtin_amdgcn_sched_barrier(0);                   // no hoisting

        floatx4 a = *(const floatx4*)((const uchar_t*)accT + (size_t)hu * 32 + bloc * 16);
        uchar_t hv = lstm_gate(a, xw, cc);
        hb8[(s + 1) & 1][bloc * HPAD + hu] = hv;

        xw = xwn;
        __syncthreads();                        // h(s+1) complete (WG-wide)

        if (tid < 64) {
            int b_ = tid >> 5, off = (tid & 31) * 8;
            ull_t v = *(const ull_t*)(&hb8[(s + 1) & 1][b_ * HPAD + off]);
            *(ull_t*)(hhist8 + ((size_t)(d * NT + t) * NB + bg * 2 + b_) * NH + off) = v;
        }
    }
}

// ---------------- K4: em[t,b,l] = feats . W_lin[l] + b_lin ------------------
__global__ void em_k(const uchar_t* __restrict__ hhist8, const float* __restrict__ Wlin,
                     const float* __restrict__ blin, float* __restrict__ em) {
    const int t = blockIdx.x;
    const int tid = threadIdx.x;          // 576 threads
    __shared__ float Ws[NL * 520];
    for (int idx = tid; idx < NL * 2 * NH; idx += 576) {
        int l = idx >> 9, k = idx & 511;
        Ws[l * 520 + k] = Wlin[l * 2 * NH + k];
    }
    __syncthreads();
    const int b = tid / NL, l = tid - b * NL;
    const uchar_t* hf = hhist8 + ((size_t)t * NB + b) * NH;
    const uchar_t* hb = hhist8 + ((size_t)(NT + t) * NB + b) * NH;
    float acc = blin[l];
    #pragma unroll 4
    for (int kc = 0; kc < NH / 4; ++kc) {
        uint_t u = *(const uint_t*)(hf + kc * 4);
        floatx2 p0 = __builtin_amdgcn_cvt_pk_f32_fp8(u, false);
        floatx2 p1 = __builtin_amdgcn_cvt_pk_f32_fp8(u, true);
        acc += p0.x * Ws[l * 520 + kc * 4]     + p0.y * Ws[l * 520 + kc * 4 + 1]
             + p1.x * Ws[l * 520 + kc * 4 + 2] + p1.y * Ws[l * 520 + kc * 4 + 3];
    }
    #pragma unroll 4
    for (int kc = 0; kc < NH / 4; ++kc) {
        uint_t u = *(const uint_t*)(hb + kc * 4);
        floatx2 p0 = __builtin_amdgcn_cvt_pk_f32_fp8(u, false);
        floatx2 p1 = __builtin_amdgcn_cvt_pk_f32_fp8(u, true);
        acc += p0.x * Ws[l * 520 + NH + kc * 4]     + p0.y * Ws[l * 520 + NH + kc * 4 + 1]
             + p1.x * Ws[l * 520 + NH + kc * 4 + 2] + p1.y * Ws[l * 520 + NH + kc * 4 + 3];
    }
    em[((size_t)t * NB + b) * NL + l] = acc;
}

// ---------------- K5: CRF numerator per batch (parallel over t) -------------
__global__ void num_k(const float* __restrict__ em, const int* __restrict__ mask,
                      const int* __restrict__ labels, const float* __restrict__ start,
                      const float* __restrict__ endt, const float* __restrict__ trans,
                      float* __restrict__ numbuf) {
    const int b = blockIdx.x;       // 64 blocks x 64 threads (1 wave)
    const int lane = threadIdx.x;
    int cntm = 0;
    for (int t = lane; t < NT; t += 64) cntm += (mask[b * NT + t] != 0);
    #pragma unroll
    for (int off = 32; off > 0; off >>= 1) cntm += __shfl_down(cntm, off);
    const int len = __shfl(cntm, 0);

    float part = 0.f;
    for (int t = lane; t < NT; t += 64) {
        if (t >= 1 && t < len) {
            int tp = labels[b * NT + t - 1];
            int tg = labels[b * NT + t];
            part += trans[tp * NL + tg] + em[((size_t)t * NB + b) * NL + tg];
        }
    }
    #pragma unroll
    for (int off = 32; off > 0; off >>= 1) part += __shfl_down(part, off);
    if (lane == 0) {
        int tag0 = labels[b * NT];
        numbuf[b] = part + start[tag0] + em[(size_t)b * NL + tag0]
                  + endt[labels[b * NT + len - 1]];
    }
}

// ---------------- K6: CRF forward (logZ), diff = logZ - num -----------------
__global__ void crf_k(const float* __restrict__ em, const int* __restrict__ mask,
                      const float* __restrict__ start, const float* __restrict__ endt,
                      const float* __restrict__ trans, const float* __restrict__ numbuf,
                      float* __restrict__ diff) {
    const int b = blockIdx.x;
    const int lane = threadIdx.x;       // 64 threads = 1 wave
    int cnt = 0;
    for (int t = lane; t < NT; t += 64) cnt += (mask[b * NT + t] != 0);
    #pragma unroll
    for (int off = 32; off > 0; off >>= 1) cnt += __shfl_down(cnt, off);
    const int len = __shfl(cnt, 0);

    float tcol[NL];
    #pragma unroll
    for (int i = 0; i < NL; ++i) tcol[i] = (lane < NL) ? trans[i * NL + lane] : 0.f;
    float endv = (lane < NL) ? endt[lane] : 0.f;
    float score = (lane < NL) ? start[lane] + em[(size_t)b * NL + lane] : -1e30f;

    for (int t = 1; t < len; ++t) {
        float emv = (lane < NL) ? em[((size_t)t * NB + b) * NL + lane] : 0.f;
        float sv[NL];
        #pragma unroll
        for (int i = 0; i < NL; ++i) sv[i] = __shfl(score, i) + tcol[i];
        float m = sv[0];
        #pragma unroll
        for (int i = 1; i < NL; ++i) m = fmaxf(m, sv[i]);
        float sum = 0.f;
        #pragma unroll
        for (int i = 0; i < NL; ++i) sum += __expf(sv[i] - m);
        float nxt = m + __logf(sum) + emv;
        if (lane < NL) score = nxt;
    }
    float v = (lane < NL) ? score + endv : -1e30f;
    float m = -1e30f;
    float sv[NL];
    #pragma unroll
    for (int i = 0; i < NL; ++i) { sv[i] = __shfl(v, i); m = fmaxf(m, sv[i]); }
    float sum = 0.f;
    #pragma unroll
    for (int i = 0; i < NL; ++i) sum += __expf(sv[i] - m);
    float logZ = m + __logf(sum);
    if (lane == 0) diff[b] = logZ - numbuf[b];
}

// ---------------- K7: mean over batch -> d_out ------------------------------
__global__ void final_k(const float* __restrict__ diff, float* __restrict__ out) {
    float v = diff[threadIdx.x];
    #pragma unroll
    for (int off = 32; off > 0; off >>= 1) v += __shfl_down(v, off);
    if (threadIdx.x == 0) out[0] = v * (1.0f / NB);
}

extern "C" void kernel_launch(void* const* d_in, const int* in_sizes, int n_in,
                              void* d_out, int out_size, void* d_ws, size_t ws_size,
                              hipStream_t stream) {
    const float* emb   = (const float*)d_in[0];
    const float* Wihf  = (const float*)d_in[1];
    const float* Whhf  = (const float*)d_in[2];
    const float* bf    = (const float*)d_in[3];
    const float* Wihb  = (const float*)d_in[4];
    const float* Whhb  = (const float*)d_in[5];
    const float* bb    = (const float*)d_in[6];
    const float* Wlin  = (const float*)d_in[7];
    const float* blin  = (const float*)d_in[8];
    const float* start = (const float*)d_in[9];
    const float* endt  = (const float*)d_in[10];
    const float* trans = (const float*)d_in[11];
    const int*   mask  = (const int*)d_in[12];
    const int*   labels= (const int*)d_in[13];

    char* ws = (char*)d_ws;
    uchar_t*  xbf8  = (uchar_t*) (ws + 0);                     // 25,165,824
    uchar_t*  wcat8 = (uchar_t*) (ws + 50331648);              //  1,572,864
    uchar_t*  whh8  = (uchar_t*) (ws + 53477376);              //    524,288
    float*    bias  = (float*)   (ws + 54001664);              //      8,192
    ushort_t* xg    = (ushort_t*)(ws + 54009856);              // 134,217,728
    uchar_t*  hh8   = (uchar_t*) (ws + 188227584);             // 16,777,216
    float*    em    = (float*)   (ws + 205004800);             //  1,179,648
    float*    numb  = (float*)   (ws + 206184448);             //        256
    float*    diff  = (float*)   (ws + 206184704);             //        256

    conv_x<<<NT * NB * (NE / 4) / 256, 256, 0, stream>>>(emb, xbf8);
    conv_w<<<(NCC * NE / 2 + NCC * NH / 2 + NCC) / 256, 256, 0, stream>>>(
        Wihf, Wihb, Whhf, Whhb, bf, bb, wcat8, whh8, bias);
    gemm_xg<<<dim3(NCC / 128, NT * NB / 128), 256, 0, stream>>>(xbf8, wcat8, bias, xg);
    lstm_k<<<64, 512, 0, stream>>>(xg, whh8, hh8);
    em_k<<<NT, 576, 0, stream>>>(hh8, Wlin, blin, em);
    num_k<<<NB, 64, 0, stream>>>(em, mask, labels, start, endt, trans, numb);
    crf_k<<<NB, 64, 0, stream>>>(em, mask, start, endt, trans, numb, diff);
    final_k<<<1, 64, 0, stream>>>(diff, (float*)d_out);
}